// Round 5
// baseline (419.187 us; speedup 1.0000x reference)
//
#include <hip/hip_runtime.h>
#include <hip/hip_bf16.h>

#define DD 128
#define BK 64   // nodes per bucket (power of 2)

typedef __attribute__((ext_vector_type(8))) short short8v;
typedef __attribute__((ext_vector_type(4))) float f32x4;

static __device__ __forceinline__ ushort f2bf(float f) {
    __hip_bfloat16 b = __float2bfloat16(f);
    return *reinterpret_cast<ushort*>(&b);
}

// ---------------- CSR build ----------------

__global__ void k_count(const int* __restrict__ ei, int* __restrict__ cnt, int E) {
    int e = blockIdx.x * blockDim.x + threadIdx.x;
    if (e < E) atomicAdd(&cnt[ei[E + e]], 1);
}

// two-level scan: one node per thread
__global__ __launch_bounds__(256) void k_scan1(const int* __restrict__ cnt,
                                               int* __restrict__ incl,
                                               int* __restrict__ bsum, int n) {
    __shared__ int s[256];
    int t = threadIdx.x;
    int i = blockIdx.x * 256 + t;
    int v = (i < n) ? cnt[i] : 0;
    s[t] = v;
    __syncthreads();
#pragma unroll
    for (int off = 1; off < 256; off <<= 1) {
        int u = (t >= off) ? s[t - off] : 0;
        __syncthreads();
        s[t] += u;
        __syncthreads();
    }
    if (i < n) incl[i] = s[t];
    if (t == 255) bsum[blockIdx.x] = s[255];
}

__global__ __launch_bounds__(256) void k_scan2(int* __restrict__ bsum, int nb) {
    __shared__ int s[256];
    int t = threadIdx.x;
    s[t] = (t < nb) ? bsum[t] : 0;
    __syncthreads();
#pragma unroll
    for (int off = 1; off < 256; off <<= 1) {
        int u = (t >= off) ? s[t - off] : 0;
        __syncthreads();
        s[t] += u;
        __syncthreads();
    }
    if (t < nb) bsum[t] = (t == 0) ? 0 : s[t - 1];
}

__global__ __launch_bounds__(256) void k_scan3(const int* __restrict__ cnt,
                                               const int* __restrict__ incl,
                                               const int* __restrict__ bsum,
                                               int* __restrict__ rowptr,
                                               int* __restrict__ cursor,
                                               int n, int E) {
    int i = blockIdx.x * 256 + threadIdx.x;
    if (i < n) {
        int r = bsum[blockIdx.x] + incl[i] - cnt[i];
        rowptr[i] = r;
        cursor[i] = r;
    }
    if (i == 0) rowptr[n] = E;
}

// bucket cursors: bcur[b] = rowptr[min(b*BK, n)]
__global__ __launch_bounds__(256) void k_bcur(const int* __restrict__ rowptr,
                                              int* __restrict__ bcur, int n, int nb) {
    int b = blockIdx.x * 256 + threadIdx.x;
    if (b < nb) {
        int node = b * BK;
        if (node > n) node = n;
        bcur[b] = rowptr[node];
    }
}

// pass A: scatter (src,dst) records into per-bucket contiguous regions
__global__ void k_bucket(const int* __restrict__ ei, int* __restrict__ bcur,
                         uint2* __restrict__ pairs, int E) {
    int e = blockIdx.x * blockDim.x + threadIdx.x;
    if (e < E) {
        int s = ei[e];
        int d = ei[E + e];
        int b = d / BK;
        int pos = atomicAdd(&bcur[b], 1);
        pairs[pos] = make_uint2((uint)s, (uint)d);
    }
}

// pass B: one block per bucket; scatter src into eidx via per-node cursors.
// All writes land in this bucket's contiguous eidx region (single block -> clean lines).
__global__ __launch_bounds__(256) void k_fill2(const uint2* __restrict__ pairs,
                                               const int* __restrict__ rowptr,
                                               int* __restrict__ cursor,
                                               int* __restrict__ eidx, int n) {
    int b = blockIdx.x;
    int node0 = b * BK;
    int node1 = node0 + BK;
    if (node1 > n) node1 = n;
    int beg = rowptr[node0];
    int end = rowptr[node1];
    for (int i = beg + threadIdx.x; i < end; i += 256) {
        uint2 pr = pairs[i];
        int p = atomicAdd(&cursor[pr.y], 1);
        eidx[p] = (int)pr.x;
    }
}

// ---------------- fp32 -> bf16 cast ----------------

__global__ __launch_bounds__(256) void k_cast(const float* __restrict__ x,
                                              ushort* __restrict__ xbf, int n4) {
    int i = blockIdx.x * blockDim.x + threadIdx.x;
    if (i >= n4) return;
    float4 v = reinterpret_cast<const float4*>(x)[i];
    ushort4 o;
    o.x = f2bf(v.x); o.y = f2bf(v.y); o.z = f2bf(v.z); o.w = f2bf(v.w);
    reinterpret_cast<ushort4*>(xbf)[i] = o;
}

// ---------------- weight prep: Wt[n][k] = bf16( k<128 ? Wl[k][n] : Wr[k-128][n] ) ----

__global__ __launch_bounds__(256) void k_prepw(const float* __restrict__ Wl,
                                               const float* __restrict__ Wr,
                                               ushort* __restrict__ Wt) {
    int idx = blockIdx.x * 256 + threadIdx.x;   // 128*256 = 32768
    int nn = idx >> 8, k = idx & 255;
    float v = (k < 128) ? Wl[k * 128 + nn] : Wr[(k - 128) * 128 + nn];
    Wt[nn * 256 + k] = f2bf(v);
}

// ---------------- mean aggregation (bf16 in/out, fp32 acc) ----------------
// wave per node; lane = (eg, c16): eg = lane>>4 picks edge-within-group-of-4,
// c16 = lane&15 picks the 16B column chunk. 8 edge-rows in flight per wave.

__global__ __launch_bounds__(256) void k_aggb(const ushort* __restrict__ hin,
                                              const int* __restrict__ rowptr,
                                              const int* __restrict__ eidx,
                                              ushort* __restrict__ aggout, int n) {
    int w = (int)((blockIdx.x * (unsigned)blockDim.x + threadIdx.x) >> 6);
    int lane = threadIdx.x & 63;
    if (w >= n) return;
    int eg = lane >> 4;
    int c16 = lane & 15;
    int beg = rowptr[w], end = rowptr[w + 1];
    const uint4* base = reinterpret_cast<const uint4*>(hin);  // 16 uint4 per row

    float acc[8];
#pragma unroll
    for (int i = 0; i < 8; ++i) acc[i] = 0.f;

    int e = beg;
    for (; e + 8 <= end; e += 8) {
        int n0 = eidx[e + eg];
        int n1 = eidx[e + 4 + eg];
        uint4 va = base[(size_t)n0 * 16 + c16];
        uint4 vb = base[(size_t)n1 * 16 + c16];
        acc[0] += __uint_as_float(va.x << 16);
        acc[1] += __uint_as_float(va.x & 0xffff0000u);
        acc[2] += __uint_as_float(va.y << 16);
        acc[3] += __uint_as_float(va.y & 0xffff0000u);
        acc[4] += __uint_as_float(va.z << 16);
        acc[5] += __uint_as_float(va.z & 0xffff0000u);
        acc[6] += __uint_as_float(va.w << 16);
        acc[7] += __uint_as_float(va.w & 0xffff0000u);
        acc[0] += __uint_as_float(vb.x << 16);
        acc[1] += __uint_as_float(vb.x & 0xffff0000u);
        acc[2] += __uint_as_float(vb.y << 16);
        acc[3] += __uint_as_float(vb.y & 0xffff0000u);
        acc[4] += __uint_as_float(vb.z << 16);
        acc[5] += __uint_as_float(vb.z & 0xffff0000u);
        acc[6] += __uint_as_float(vb.w << 16);
        acc[7] += __uint_as_float(vb.w & 0xffff0000u);
    }
    for (; e < end; e += 4) {
        int ee = e + eg;
        if (ee < end) {
            int n0 = eidx[ee];
            uint4 va = base[(size_t)n0 * 16 + c16];
            acc[0] += __uint_as_float(va.x << 16);
            acc[1] += __uint_as_float(va.x & 0xffff0000u);
            acc[2] += __uint_as_float(va.y << 16);
            acc[3] += __uint_as_float(va.y & 0xffff0000u);
            acc[4] += __uint_as_float(va.z << 16);
            acc[5] += __uint_as_float(va.z & 0xffff0000u);
            acc[6] += __uint_as_float(va.w << 16);
            acc[7] += __uint_as_float(va.w & 0xffff0000u);
        }
    }

    // reduce the 4 edge-groups (lanes differing in bits 4,5)
#pragma unroll
    for (int i = 0; i < 8; ++i) {
        acc[i] += __shfl_xor(acc[i], 16);
        acc[i] += __shfl_xor(acc[i], 32);
    }

    if (eg == 0) {
        float inv = 1.0f / fmaxf((float)(end - beg), 1.0f);
        uint4 o;
        o.x = ((uint)f2bf(acc[1] * inv) << 16) | (uint)f2bf(acc[0] * inv);
        o.y = ((uint)f2bf(acc[3] * inv) << 16) | (uint)f2bf(acc[2] * inv);
        o.z = ((uint)f2bf(acc[5] * inv) << 16) | (uint)f2bf(acc[4] * inv);
        o.w = ((uint)f2bf(acc[7] * inv) << 16) | (uint)f2bf(acc[6] * inv);
        reinterpret_cast<uint4*>(aggout)[(size_t)w * 16 + c16] = o;
    }
}

// ---------------- MFMA GEMM: out[m][:] = concat(Alow,Ahigh)[m][:] @ Wt^T + b ----

__global__ __launch_bounds__(256) void k_mm(const ushort* __restrict__ Alow,
                                            const ushort* __restrict__ Ahigh,
                                            const ushort* __restrict__ Wt,
                                            const float* __restrict__ bias,
                                            void* __restrict__ outp,
                                            int n, int relu, int outBf16) {
    int t = threadIdx.x;
    int wv = t >> 6;
    int l = t & 63;
    int lr = l & 15;
    int lk = l >> 4;
    int m0 = blockIdx.x * 64 + wv * 16;
    int arow = m0 + lr;
    if (arow >= n) arow = n - 1;  // clamp; stores are guarded

    f32x4 acc[8];
#pragma unroll
    for (int i = 0; i < 8; ++i) acc[i] = (f32x4){0.f, 0.f, 0.f, 0.f};

    const ushort* arow_lo = Alow + (size_t)arow * DD;
    const ushort* arow_hi = Ahigh + (size_t)arow * DD;

#pragma unroll
    for (int ks = 0; ks < 8; ++ks) {
        int k0 = ks * 32 + lk * 8;
        const ushort* asrc = (k0 < 128) ? (arow_lo + k0) : (arow_hi + (k0 - 128));
        short8v af = *reinterpret_cast<const short8v*>(asrc);
#pragma unroll
        for (int nt = 0; nt < 8; ++nt) {
            short8v bf = *reinterpret_cast<const short8v*>(Wt + (size_t)(nt * 16 + lr) * 256 + k0);
            acc[nt] = __builtin_amdgcn_mfma_f32_16x16x32_bf16(af, bf, acc[nt], 0, 0, 0);
        }
    }

    int crow0 = m0 + lk * 4;
#pragma unroll
    for (int nt = 0; nt < 8; ++nt) {
        int col = nt * 16 + lr;
        float bv = bias[col];
#pragma unroll
        for (int r = 0; r < 4; ++r) {
            int row = crow0 + r;
            if (row < n) {
                float v = acc[nt][r] + bv;
                if (relu) v = fmaxf(v, 0.f);
                if (outBf16) {
                    reinterpret_cast<ushort*>(outp)[(size_t)row * DD + col] = f2bf(v);
                } else {
                    reinterpret_cast<float*>(outp)[(size_t)row * DD + col] = v;
                }
            }
        }
    }
}

// ---------------- launch ----------------

extern "C" void kernel_launch(void* const* d_in, const int* in_sizes, int n_in,
                              void* d_out, int out_size, void* d_ws, size_t ws_size,
                              hipStream_t stream) {
    const float* x   = (const float*)d_in[0];
    const int*   ei  = (const int*)d_in[1];
    const float* Wl1 = (const float*)d_in[2];
    const float* Wr1 = (const float*)d_in[3];
    const float* b1  = (const float*)d_in[4];
    const float* Wl2 = (const float*)d_in[5];
    const float* Wr2 = (const float*)d_in[6];
    const float* b2  = (const float*)d_in[7];
    float* out = (float*)d_out;

    int n = in_sizes[0] / DD;
    int E = in_sizes[1] / 2;

    char* ws = (char*)d_ws;
    size_t off = 0;
    auto take = [&](size_t bytes) -> void* {
        void* p = ws + off;
        off = (off + bytes + 255) & ~(size_t)255;
        return p;
    };
    int* cnt       = (int*)take((size_t)n * 4);
    int* rowptr    = (int*)take(((size_t)n + 1) * 4);
    int* cursor    = (int*)take((size_t)n * 4);
    int* incl      = (int*)take((size_t)n * 4);
    int* bsum      = (int*)take(1024);
    int* bcur      = (int*)take((((size_t)n + BK - 1) / BK) * 4);
    int* eidx      = (int*)take((size_t)E * 4);
    uint2* pairs   = (uint2*)take((size_t)E * 8);
    ushort* xbf    = (ushort*)take((size_t)n * DD * 2);
    ushort* hbf    = (ushort*)take((size_t)n * DD * 2);
    ushort* aggbf  = (ushort*)take((size_t)n * DD * 2);
    ushort* Wt1    = (ushort*)take((size_t)DD * 256 * 2);
    ushort* Wt2    = (ushort*)take((size_t)DD * 256 * 2);

    int scanBlocks = (n + 255) / 256;
    int nb = (n + BK - 1) / BK;

    hipMemsetAsync(cnt, 0, (size_t)n * 4, stream);
    k_count<<<(E + 255) / 256, 256, 0, stream>>>(ei, cnt, E);
    k_scan1<<<scanBlocks, 256, 0, stream>>>(cnt, incl, bsum, n);
    k_scan2<<<1, 256, 0, stream>>>(bsum, scanBlocks);
    k_scan3<<<scanBlocks, 256, 0, stream>>>(cnt, incl, bsum, rowptr, cursor, n, E);
    k_bcur<<<(nb + 255) / 256, 256, 0, stream>>>(rowptr, bcur, n, nb);
    k_bucket<<<(E + 255) / 256, 256, 0, stream>>>(ei, bcur, pairs, E);
    k_fill2<<<nb, 256, 0, stream>>>(pairs, rowptr, cursor, eidx, n);

    int n4 = n * DD / 4;
    k_cast<<<(n4 + 255) / 256, 256, 0, stream>>>(x, xbf, n4);
    k_prepw<<<128, 256, 0, stream>>>(Wl1, Wr1, Wt1);
    k_prepw<<<128, 256, 0, stream>>>(Wl2, Wr2, Wt2);

    int aggBlocks = (n + 3) / 4;       // 4 waves (nodes) / block
    int mmBlocks  = (n + 63) / 64;     // 64 rows / block

    // Layer 1: h = relu(mean_agg(xbf) @ Wl1 + b1 + xbf @ Wr1)
    k_aggb<<<aggBlocks, 256, 0, stream>>>(xbf, rowptr, eidx, aggbf, n);
    k_mm<<<mmBlocks, 256, 0, stream>>>(aggbf, xbf, Wt1, b1, hbf, n, 1, 1);
    // Layer 2: out = mean_agg(hbf) @ Wl2 + b2 + hbf @ Wr2
    k_aggb<<<aggBlocks, 256, 0, stream>>>(hbf, rowptr, eidx, aggbf, n);
    k_mm<<<mmBlocks, 256, 0, stream>>>(aggbf, hbf, Wt2, b2, out, n, 0, 0);
}

// Round 6
// 212.066 us; speedup vs baseline: 1.9767x; 1.9767x over previous
//
#include <hip/hip_runtime.h>
#include <hip/hip_bf16.h>

#define DD 128
#define BSH 8          // 256 nodes per bucket
#define CHUNK 4096     // edges per partition block

typedef __attribute__((ext_vector_type(8))) short short8v;
typedef __attribute__((ext_vector_type(4))) float f32x4;

static __device__ __forceinline__ ushort f2bf(float f) {
    __hip_bfloat16 b = __float2bfloat16(f);
    return *reinterpret_cast<ushort*>(&b);
}

// ---------------- CSR build: chunked radix partition ----------------

// per-chunk bucket histogram (bucket = dst>>BSH)
__global__ __launch_bounds__(256) void k_hist(const int* __restrict__ ei,
                                              int* __restrict__ hist, int E, int NB) {
    __shared__ int lh[256];
    int t = threadIdx.x;
    lh[t] = 0;
    __syncthreads();
    int e0 = blockIdx.x * CHUNK;
    int e1 = min(e0 + CHUNK, E);
    for (int e = e0 + t; e < e1; e += 256)
        atomicAdd(&lh[ei[E + e] >> BSH], 1);
    __syncthreads();
    if (t < NB) hist[blockIdx.x * NB + t] = lh[t];
}

// single block: bucket bases + convert hist rows to global offsets
__global__ __launch_bounds__(1024) void k_hscan(int* __restrict__ hist,
                                                int* __restrict__ bbase,
                                                int nblk, int NB, int E) {
    __shared__ int part[4][256];
    __shared__ int s[256];
    int t = threadIdx.x;
    int b = t & 255, g = t >> 8;
    int q = (nblk + 3) >> 2;
    int lo = g * q, hi = min(lo + q, nblk);
    int sum = 0;
    if (b < NB)
        for (int blk = lo; blk < hi; ++blk) sum += hist[blk * NB + b];
    part[g][b] = sum;
    __syncthreads();
    if (g == 0) s[b] = part[0][b] + part[1][b] + part[2][b] + part[3][b];
    __syncthreads();
    for (int off = 1; off < 256; off <<= 1) {
        int v = 0;
        if (g == 0 && b >= off) v = s[b - off];
        __syncthreads();
        if (g == 0) s[b] += v;
        __syncthreads();
    }
    int base = (b == 0) ? 0 : s[b - 1];
    if (g == 0 && b < NB) bbase[b] = base;
    if (t == 0) bbase[NB] = E;
    int run = base;
    for (int gg = 0; gg < g; ++gg) run += part[gg][b];
    if (b < NB)
        for (int blk = lo; blk < hi; ++blk) {
            int tmp = hist[blk * NB + b];
            hist[blk * NB + b] = run;
            run += tmp;
        }
}

// scatter (src,dst) records into bucket-grouped pairs[], LDS-local positions
__global__ __launch_bounds__(256) void k_scatter(const int* __restrict__ ei,
                                                 const int* __restrict__ hist,
                                                 uint2* __restrict__ pairs, int E, int NB) {
    __shared__ int lofs[256];
    __shared__ int lh[256];
    int t = threadIdx.x;
    int blk = blockIdx.x;
    lh[t] = 0;
    if (t < NB) lofs[t] = hist[blk * NB + t];
    __syncthreads();
    int e0 = blk * CHUNK, e1 = min(e0 + CHUNK, E);
    for (int e = e0 + t; e < e1; e += 256) {
        int sN = ei[e];
        int d = ei[E + e];
        int b = d >> BSH;
        int lp = atomicAdd(&lh[b], 1);
        pairs[lofs[b] + lp] = make_uint2((uint)sN, (uint)d);
    }
}

// per-node counts from bucket regions (LDS atomics, coalesced writeout)
__global__ __launch_bounds__(256) void k_cntb(const uint2* __restrict__ pairs,
                                              const int* __restrict__ bbase,
                                              int* __restrict__ cnt, int n) {
    __shared__ int lc[256];
    int t = threadIdx.x;
    int b = blockIdx.x;
    lc[t] = 0;
    __syncthreads();
    int node0 = b << BSH;
    int r0 = bbase[b], r1 = bbase[b + 1];
    for (int i = r0 + t; i < r1; i += 256)
        atomicAdd(&lc[(int)pairs[i].y - node0], 1);
    __syncthreads();
    int node = node0 + t;
    if (node < n) cnt[node] = lc[t];
}

// two-level scan: one node per thread
__global__ __launch_bounds__(256) void k_scan1(const int* __restrict__ cnt,
                                               int* __restrict__ incl,
                                               int* __restrict__ bsum, int n) {
    __shared__ int s[256];
    int t = threadIdx.x;
    int i = blockIdx.x * 256 + t;
    int v = (i < n) ? cnt[i] : 0;
    s[t] = v;
    __syncthreads();
#pragma unroll
    for (int off = 1; off < 256; off <<= 1) {
        int u = (t >= off) ? s[t - off] : 0;
        __syncthreads();
        s[t] += u;
        __syncthreads();
    }
    if (i < n) incl[i] = s[t];
    if (t == 255) bsum[blockIdx.x] = s[255];
}

__global__ __launch_bounds__(256) void k_scan2(int* __restrict__ bsum, int nb) {
    __shared__ int s[256];
    int t = threadIdx.x;
    s[t] = (t < nb) ? bsum[t] : 0;
    __syncthreads();
#pragma unroll
    for (int off = 1; off < 256; off <<= 1) {
        int u = (t >= off) ? s[t - off] : 0;
        __syncthreads();
        s[t] += u;
        __syncthreads();
    }
    if (t < nb) bsum[t] = (t == 0) ? 0 : s[t - 1];
}

__global__ __launch_bounds__(256) void k_scan3(const int* __restrict__ cnt,
                                               const int* __restrict__ incl,
                                               const int* __restrict__ bsum,
                                               int* __restrict__ rowptr,
                                               int n, int E) {
    int i = blockIdx.x * 256 + threadIdx.x;
    if (i < n) rowptr[i] = bsum[blockIdx.x] + incl[i] - cnt[i];
    if (i == 0) rowptr[n] = E;
}

// final fill: one block per bucket, LDS per-node cursors, local eidx region
__global__ __launch_bounds__(256) void k_fill3(const uint2* __restrict__ pairs,
                                               const int* __restrict__ bbase,
                                               const int* __restrict__ rowptr,
                                               int* __restrict__ eidx, int n) {
    __shared__ int cur[256];
    int t = threadIdx.x;
    int b = blockIdx.x;
    int node0 = b << BSH;
    int node = node0 + t;
    cur[t] = (node < n) ? rowptr[node] : 0;
    __syncthreads();
    int r0 = bbase[b], r1 = bbase[b + 1];
    for (int i = r0 + t; i < r1; i += 256) {
        uint2 pr = pairs[i];
        int p = atomicAdd(&cur[(int)pr.y - node0], 1);
        eidx[p] = (int)pr.x;
    }
}

// ---------------- fp32 -> bf16 cast ----------------

__global__ __launch_bounds__(256) void k_cast(const float* __restrict__ x,
                                              ushort* __restrict__ xbf, int n4) {
    int i = blockIdx.x * blockDim.x + threadIdx.x;
    if (i >= n4) return;
    float4 v = reinterpret_cast<const float4*>(x)[i];
    ushort4 o;
    o.x = f2bf(v.x); o.y = f2bf(v.y); o.z = f2bf(v.z); o.w = f2bf(v.w);
    reinterpret_cast<ushort4*>(xbf)[i] = o;
}

// ---------------- weight prep: Wt[n][k] = bf16( k<128 ? Wl[k][n] : Wr[k-128][n] ) ----

__global__ __launch_bounds__(256) void k_prepw(const float* __restrict__ Wl,
                                               const float* __restrict__ Wr,
                                               ushort* __restrict__ Wt) {
    int idx = blockIdx.x * 256 + threadIdx.x;   // 128*256 = 32768
    int nn = idx >> 8, k = idx & 255;
    float v = (k < 128) ? Wl[k * 128 + nn] : Wr[(k - 128) * 128 + nn];
    Wt[nn * 256 + k] = f2bf(v);
}

// ---------------- mean aggregation (bf16 in/out, fp32 acc) ----------------

__global__ __launch_bounds__(256) void k_aggb(const ushort* __restrict__ hin,
                                              const int* __restrict__ rowptr,
                                              const int* __restrict__ eidx,
                                              ushort* __restrict__ aggout, int n) {
    int w = (int)((blockIdx.x * (unsigned)blockDim.x + threadIdx.x) >> 6);
    int lane = threadIdx.x & 63;
    if (w >= n) return;
    int eg = lane >> 4;
    int c16 = lane & 15;
    int beg = rowptr[w], end = rowptr[w + 1];
    const uint4* base = reinterpret_cast<const uint4*>(hin);  // 16 uint4 per row

    float acc[8];
#pragma unroll
    for (int i = 0; i < 8; ++i) acc[i] = 0.f;

    int e = beg;
    for (; e + 8 <= end; e += 8) {
        int n0 = eidx[e + eg];
        int n1 = eidx[e + 4 + eg];
        uint4 va = base[(size_t)n0 * 16 + c16];
        uint4 vb = base[(size_t)n1 * 16 + c16];
        acc[0] += __uint_as_float(va.x << 16);
        acc[1] += __uint_as_float(va.x & 0xffff0000u);
        acc[2] += __uint_as_float(va.y << 16);
        acc[3] += __uint_as_float(va.y & 0xffff0000u);
        acc[4] += __uint_as_float(va.z << 16);
        acc[5] += __uint_as_float(va.z & 0xffff0000u);
        acc[6] += __uint_as_float(va.w << 16);
        acc[7] += __uint_as_float(va.w & 0xffff0000u);
        acc[0] += __uint_as_float(vb.x << 16);
        acc[1] += __uint_as_float(vb.x & 0xffff0000u);
        acc[2] += __uint_as_float(vb.y << 16);
        acc[3] += __uint_as_float(vb.y & 0xffff0000u);
        acc[4] += __uint_as_float(vb.z << 16);
        acc[5] += __uint_as_float(vb.z & 0xffff0000u);
        acc[6] += __uint_as_float(vb.w << 16);
        acc[7] += __uint_as_float(vb.w & 0xffff0000u);
    }
    for (; e < end; e += 4) {
        int ee = e + eg;
        if (ee < end) {
            int n0 = eidx[ee];
            uint4 va = base[(size_t)n0 * 16 + c16];
            acc[0] += __uint_as_float(va.x << 16);
            acc[1] += __uint_as_float(va.x & 0xffff0000u);
            acc[2] += __uint_as_float(va.y << 16);
            acc[3] += __uint_as_float(va.y & 0xffff0000u);
            acc[4] += __uint_as_float(va.z << 16);
            acc[5] += __uint_as_float(va.z & 0xffff0000u);
            acc[6] += __uint_as_float(va.w << 16);
            acc[7] += __uint_as_float(va.w & 0xffff0000u);
        }
    }

#pragma unroll
    for (int i = 0; i < 8; ++i) {
        acc[i] += __shfl_xor(acc[i], 16);
        acc[i] += __shfl_xor(acc[i], 32);
    }

    if (eg == 0) {
        float inv = 1.0f / fmaxf((float)(end - beg), 1.0f);
        uint4 o;
        o.x = ((uint)f2bf(acc[1] * inv) << 16) | (uint)f2bf(acc[0] * inv);
        o.y = ((uint)f2bf(acc[3] * inv) << 16) | (uint)f2bf(acc[2] * inv);
        o.z = ((uint)f2bf(acc[5] * inv) << 16) | (uint)f2bf(acc[4] * inv);
        o.w = ((uint)f2bf(acc[7] * inv) << 16) | (uint)f2bf(acc[6] * inv);
        reinterpret_cast<uint4*>(aggout)[(size_t)w * 16 + c16] = o;
    }
}

// ---------------- MFMA GEMM: out[m][:] = concat(Alow,Ahigh)[m][:] @ Wt^T + b ----

__global__ __launch_bounds__(256) void k_mm(const ushort* __restrict__ Alow,
                                            const ushort* __restrict__ Ahigh,
                                            const ushort* __restrict__ Wt,
                                            const float* __restrict__ bias,
                                            void* __restrict__ outp,
                                            int n, int relu, int outBf16) {
    int t = threadIdx.x;
    int wv = t >> 6;
    int l = t & 63;
    int lr = l & 15;
    int lk = l >> 4;
    int m0 = blockIdx.x * 64 + wv * 16;
    int arow = m0 + lr;
    if (arow >= n) arow = n - 1;  // clamp; stores are guarded

    f32x4 acc[8];
#pragma unroll
    for (int i = 0; i < 8; ++i) acc[i] = (f32x4){0.f, 0.f, 0.f, 0.f};

    const ushort* arow_lo = Alow + (size_t)arow * DD;
    const ushort* arow_hi = Ahigh + (size_t)arow * DD;

#pragma unroll
    for (int ks = 0; ks < 8; ++ks) {
        int k0 = ks * 32 + lk * 8;
        const ushort* asrc = (k0 < 128) ? (arow_lo + k0) : (arow_hi + (k0 - 128));
        short8v af = *reinterpret_cast<const short8v*>(asrc);
#pragma unroll
        for (int nt = 0; nt < 8; ++nt) {
            short8v bf = *reinterpret_cast<const short8v*>(Wt + (size_t)(nt * 16 + lr) * 256 + k0);
            acc[nt] = __builtin_amdgcn_mfma_f32_16x16x32_bf16(af, bf, acc[nt], 0, 0, 0);
        }
    }

    int crow0 = m0 + lk * 4;
#pragma unroll
    for (int nt = 0; nt < 8; ++nt) {
        int col = nt * 16 + lr;
        float bv = bias[col];
#pragma unroll
        for (int r = 0; r < 4; ++r) {
            int row = crow0 + r;
            if (row < n) {
                float v = acc[nt][r] + bv;
                if (relu) v = fmaxf(v, 0.f);
                if (outBf16) {
                    reinterpret_cast<ushort*>(outp)[(size_t)row * DD + col] = f2bf(v);
                } else {
                    reinterpret_cast<float*>(outp)[(size_t)row * DD + col] = v;
                }
            }
        }
    }
}

// ---------------- launch ----------------

extern "C" void kernel_launch(void* const* d_in, const int* in_sizes, int n_in,
                              void* d_out, int out_size, void* d_ws, size_t ws_size,
                              hipStream_t stream) {
    const float* x   = (const float*)d_in[0];
    const int*   ei  = (const int*)d_in[1];
    const float* Wl1 = (const float*)d_in[2];
    const float* Wr1 = (const float*)d_in[3];
    const float* b1  = (const float*)d_in[4];
    const float* Wl2 = (const float*)d_in[5];
    const float* Wr2 = (const float*)d_in[6];
    const float* b2  = (const float*)d_in[7];
    float* out = (float*)d_out;

    int n = in_sizes[0] / DD;
    int E = in_sizes[1] / 2;

    int NB   = (n + 255) >> 8;          // buckets (<=256 for n<=65536)
    int nblk = (E + CHUNK - 1) / CHUNK; // partition chunks

    char* ws = (char*)d_ws;
    size_t off = 0;
    auto take = [&](size_t bytes) -> void* {
        void* p = ws + off;
        off = (off + bytes + 255) & ~(size_t)255;
        return p;
    };
    int* cnt       = (int*)take((size_t)n * 4);
    int* rowptr    = (int*)take(((size_t)n + 1) * 4);
    int* incl      = (int*)take((size_t)n * 4);
    int* bsum      = (int*)take(1024);
    int* hist      = (int*)take((size_t)nblk * NB * 4);
    int* bbase     = (int*)take(((size_t)NB + 1) * 4);
    int* eidx      = (int*)take((size_t)E * 4);
    uint2* pairs   = (uint2*)take((size_t)E * 8);
    ushort* xbf    = (ushort*)take((size_t)n * DD * 2);
    ushort* hbf    = (ushort*)take((size_t)n * DD * 2);
    ushort* aggbf  = (ushort*)take((size_t)n * DD * 2);
    ushort* Wt1    = (ushort*)take((size_t)DD * 256 * 2);
    ushort* Wt2    = (ushort*)take((size_t)DD * 256 * 2);

    int scanBlocks = (n + 255) / 256;

    // CSR build
    k_hist<<<nblk, 256, 0, stream>>>(ei, hist, E, NB);
    k_hscan<<<1, 1024, 0, stream>>>(hist, bbase, nblk, NB, E);
    k_scatter<<<nblk, 256, 0, stream>>>(ei, hist, pairs, E, NB);
    k_cntb<<<NB, 256, 0, stream>>>(pairs, bbase, cnt, n);
    k_scan1<<<scanBlocks, 256, 0, stream>>>(cnt, incl, bsum, n);
    k_scan2<<<1, 256, 0, stream>>>(bsum, scanBlocks);
    k_scan3<<<scanBlocks, 256, 0, stream>>>(cnt, incl, bsum, rowptr, n, E);
    k_fill3<<<NB, 256, 0, stream>>>(pairs, bbase, rowptr, eidx, n);

    // dtype prep
    int n4 = n * DD / 4;
    k_cast<<<(n4 + 255) / 256, 256, 0, stream>>>(x, xbf, n4);
    k_prepw<<<128, 256, 0, stream>>>(Wl1, Wr1, Wt1);
    k_prepw<<<128, 256, 0, stream>>>(Wl2, Wr2, Wt2);

    int aggBlocks = (n + 3) / 4;       // 4 waves (nodes) / block
    int mmBlocks  = (n + 63) / 64;     // 64 rows / block

    // Layer 1: h = relu(mean_agg(xbf) @ Wl1 + b1 + xbf @ Wr1)
    k_aggb<<<aggBlocks, 256, 0, stream>>>(xbf, rowptr, eidx, aggbf, n);
    k_mm<<<mmBlocks, 256, 0, stream>>>(aggbf, xbf, Wt1, b1, hbf, n, 1, 1);
    // Layer 2: out = mean_agg(hbf) @ Wl2 + b2 + hbf @ Wr2
    k_aggb<<<aggBlocks, 256, 0, stream>>>(hbf, rowptr, eidx, aggbf, n);
    k_mm<<<mmBlocks, 256, 0, stream>>>(aggbf, hbf, Wt2, b2, out, n, 0, 0);
}

// Round 7
// 198.058 us; speedup vs baseline: 2.1165x; 1.0707x over previous
//
#include <hip/hip_runtime.h>
#include <hip/hip_bf16.h>

#define DD 128
#define BSH 8          // 256 nodes per bucket
#define CHUNK 4096     // edges per partition block
#define MM_STREAMS 1024

typedef __attribute__((ext_vector_type(8))) short short8v;
typedef __attribute__((ext_vector_type(4))) float f32x4;

static __device__ __forceinline__ ushort f2bf(float f) {
    __hip_bfloat16 b = __float2bfloat16(f);
    return *reinterpret_cast<ushort*>(&b);
}

// ---------------- CSR build: chunked radix partition ----------------

__global__ __launch_bounds__(256) void k_hist(const int* __restrict__ ei,
                                              int* __restrict__ hist, int E, int NB) {
    __shared__ int lh[256];
    int t = threadIdx.x;
    lh[t] = 0;
    __syncthreads();
    int e0 = blockIdx.x * CHUNK;
    int e1 = min(e0 + CHUNK, E);
    for (int e = e0 + t; e < e1; e += 256)
        atomicAdd(&lh[ei[E + e] >> BSH], 1);
    __syncthreads();
    if (t < NB) hist[blockIdx.x * NB + t] = lh[t];
}

__global__ __launch_bounds__(1024) void k_hscan(int* __restrict__ hist,
                                                int* __restrict__ bbase,
                                                int nblk, int NB, int E) {
    __shared__ int part[4][256];
    __shared__ int s[256];
    int t = threadIdx.x;
    int b = t & 255, g = t >> 8;
    int q = (nblk + 3) >> 2;
    int lo = g * q, hi = min(lo + q, nblk);
    int sum = 0;
    if (b < NB)
        for (int blk = lo; blk < hi; ++blk) sum += hist[blk * NB + b];
    part[g][b] = sum;
    __syncthreads();
    if (g == 0) s[b] = part[0][b] + part[1][b] + part[2][b] + part[3][b];
    __syncthreads();
    for (int off = 1; off < 256; off <<= 1) {
        int v = 0;
        if (g == 0 && b >= off) v = s[b - off];
        __syncthreads();
        if (g == 0) s[b] += v;
        __syncthreads();
    }
    int base = (b == 0) ? 0 : s[b - 1];
    if (g == 0 && b < NB) bbase[b] = base;
    if (t == 0) bbase[NB] = E;
    int run = base;
    for (int gg = 0; gg < g; ++gg) run += part[gg][b];
    if (b < NB)
        for (int blk = lo; blk < hi; ++blk) {
            int tmp = hist[blk * NB + b];
            hist[blk * NB + b] = run;
            run += tmp;
        }
}

__global__ __launch_bounds__(256) void k_scatter(const int* __restrict__ ei,
                                                 const int* __restrict__ hist,
                                                 uint2* __restrict__ pairs, int E, int NB) {
    __shared__ int lofs[256];
    __shared__ int lh[256];
    int t = threadIdx.x;
    int blk = blockIdx.x;
    lh[t] = 0;
    if (t < NB) lofs[t] = hist[blk * NB + t];
    __syncthreads();
    int e0 = blk * CHUNK, e1 = min(e0 + CHUNK, E);
    for (int e = e0 + t; e < e1; e += 256) {
        int sN = ei[e];
        int d = ei[E + e];
        int b = d >> BSH;
        int lp = atomicAdd(&lh[b], 1);
        pairs[lofs[b] + lp] = make_uint2((uint)sN, (uint)d);
    }
}

__global__ __launch_bounds__(256) void k_cntb(const uint2* __restrict__ pairs,
                                              const int* __restrict__ bbase,
                                              int* __restrict__ cnt, int n) {
    __shared__ int lc[256];
    int t = threadIdx.x;
    int b = blockIdx.x;
    lc[t] = 0;
    __syncthreads();
    int node0 = b << BSH;
    int r0 = bbase[b], r1 = bbase[b + 1];
    for (int i = r0 + t; i < r1; i += 256)
        atomicAdd(&lc[(int)pairs[i].y - node0], 1);
    __syncthreads();
    int node = node0 + t;
    if (node < n) cnt[node] = lc[t];
}

__global__ __launch_bounds__(256) void k_scan1(const int* __restrict__ cnt,
                                               int* __restrict__ incl,
                                               int* __restrict__ bsum, int n) {
    __shared__ int s[256];
    int t = threadIdx.x;
    int i = blockIdx.x * 256 + t;
    int v = (i < n) ? cnt[i] : 0;
    s[t] = v;
    __syncthreads();
#pragma unroll
    for (int off = 1; off < 256; off <<= 1) {
        int u = (t >= off) ? s[t - off] : 0;
        __syncthreads();
        s[t] += u;
        __syncthreads();
    }
    if (i < n) incl[i] = s[t];
    if (t == 255) bsum[blockIdx.x] = s[255];
}

__global__ __launch_bounds__(256) void k_scan2(int* __restrict__ bsum, int nb) {
    __shared__ int s[256];
    int t = threadIdx.x;
    s[t] = (t < nb) ? bsum[t] : 0;
    __syncthreads();
#pragma unroll
    for (int off = 1; off < 256; off <<= 1) {
        int u = (t >= off) ? s[t - off] : 0;
        __syncthreads();
        s[t] += u;
        __syncthreads();
    }
    if (t < nb) bsum[t] = (t == 0) ? 0 : s[t - 1];
}

__global__ __launch_bounds__(256) void k_scan3(const int* __restrict__ cnt,
                                               const int* __restrict__ incl,
                                               const int* __restrict__ bsum,
                                               int* __restrict__ rowptr,
                                               int n, int E) {
    int i = blockIdx.x * 256 + threadIdx.x;
    if (i < n) rowptr[i] = bsum[blockIdx.x] + incl[i] - cnt[i];
    if (i == 0) rowptr[n] = E;
}

__global__ __launch_bounds__(256) void k_fill3(const uint2* __restrict__ pairs,
                                               const int* __restrict__ bbase,
                                               const int* __restrict__ rowptr,
                                               int* __restrict__ eidx, int n) {
    __shared__ int cur[256];
    int t = threadIdx.x;
    int b = blockIdx.x;
    int node0 = b << BSH;
    int node = node0 + t;
    cur[t] = (node < n) ? rowptr[node] : 0;
    __syncthreads();
    int r0 = bbase[b], r1 = bbase[b + 1];
    for (int i = r0 + t; i < r1; i += 256) {
        uint2 pr = pairs[i];
        int p = atomicAdd(&cur[(int)pr.y - node0], 1);
        eidx[p] = (int)pr.x;
    }
}

// ---------------- fp32 -> bf16 cast ----------------

__global__ __launch_bounds__(256) void k_cast(const float* __restrict__ x,
                                              ushort* __restrict__ xbf, int n4) {
    int i = blockIdx.x * blockDim.x + threadIdx.x;
    if (i >= n4) return;
    float4 v = reinterpret_cast<const float4*>(x)[i];
    ushort4 o;
    o.x = f2bf(v.x); o.y = f2bf(v.y); o.z = f2bf(v.z); o.w = f2bf(v.w);
    reinterpret_cast<ushort4*>(xbf)[i] = o;
}

// ---------------- weight prep: Wt[n][k] = bf16( k<128 ? Wl[k][n] : Wr[k-128][n] ) ----

__global__ __launch_bounds__(256) void k_prepw(const float* __restrict__ Wl,
                                               const float* __restrict__ Wr,
                                               ushort* __restrict__ Wt) {
    int idx = blockIdx.x * 256 + threadIdx.x;   // 128*256 = 32768
    int nn = idx >> 8, k = idx & 255;
    float v = (k < 128) ? Wl[k * 128 + nn] : Wr[(k - 128) * 128 + nn];
    Wt[nn * 256 + k] = f2bf(v);
}

// ---------------- mean aggregation (bf16 in/out, fp32 acc) ----------------

__global__ __launch_bounds__(256) void k_aggb(const ushort* __restrict__ hin,
                                              const int* __restrict__ rowptr,
                                              const int* __restrict__ eidx,
                                              ushort* __restrict__ aggout, int n) {
    int w = (int)((blockIdx.x * (unsigned)blockDim.x + threadIdx.x) >> 6);
    int lane = threadIdx.x & 63;
    if (w >= n) return;
    int eg = lane >> 4;
    int c16 = lane & 15;
    int beg = rowptr[w], end = rowptr[w + 1];
    const uint4* base = reinterpret_cast<const uint4*>(hin);  // 16 uint4 per row

    float acc[8];
#pragma unroll
    for (int i = 0; i < 8; ++i) acc[i] = 0.f;

    int e = beg;
    for (; e + 8 <= end; e += 8) {
        int n0 = eidx[e + eg];
        int n1 = eidx[e + 4 + eg];
        uint4 va = base[(size_t)n0 * 16 + c16];
        uint4 vb = base[(size_t)n1 * 16 + c16];
        acc[0] += __uint_as_float(va.x << 16);
        acc[1] += __uint_as_float(va.x & 0xffff0000u);
        acc[2] += __uint_as_float(va.y << 16);
        acc[3] += __uint_as_float(va.y & 0xffff0000u);
        acc[4] += __uint_as_float(va.z << 16);
        acc[5] += __uint_as_float(va.z & 0xffff0000u);
        acc[6] += __uint_as_float(va.w << 16);
        acc[7] += __uint_as_float(va.w & 0xffff0000u);
        acc[0] += __uint_as_float(vb.x << 16);
        acc[1] += __uint_as_float(vb.x & 0xffff0000u);
        acc[2] += __uint_as_float(vb.y << 16);
        acc[3] += __uint_as_float(vb.y & 0xffff0000u);
        acc[4] += __uint_as_float(vb.z << 16);
        acc[5] += __uint_as_float(vb.z & 0xffff0000u);
        acc[6] += __uint_as_float(vb.w << 16);
        acc[7] += __uint_as_float(vb.w & 0xffff0000u);
    }
    for (; e < end; e += 4) {
        int ee = e + eg;
        if (ee < end) {
            int n0 = eidx[ee];
            uint4 va = base[(size_t)n0 * 16 + c16];
            acc[0] += __uint_as_float(va.x << 16);
            acc[1] += __uint_as_float(va.x & 0xffff0000u);
            acc[2] += __uint_as_float(va.y << 16);
            acc[3] += __uint_as_float(va.y & 0xffff0000u);
            acc[4] += __uint_as_float(va.z << 16);
            acc[5] += __uint_as_float(va.z & 0xffff0000u);
            acc[6] += __uint_as_float(va.w << 16);
            acc[7] += __uint_as_float(va.w & 0xffff0000u);
        }
    }

#pragma unroll
    for (int i = 0; i < 8; ++i) {
        acc[i] += __shfl_xor(acc[i], 16);
        acc[i] += __shfl_xor(acc[i], 32);
    }

    if (eg == 0) {
        float inv = 1.0f / fmaxf((float)(end - beg), 1.0f);
        uint4 o;
        o.x = ((uint)f2bf(acc[1] * inv) << 16) | (uint)f2bf(acc[0] * inv);
        o.y = ((uint)f2bf(acc[3] * inv) << 16) | (uint)f2bf(acc[2] * inv);
        o.z = ((uint)f2bf(acc[5] * inv) << 16) | (uint)f2bf(acc[4] * inv);
        o.w = ((uint)f2bf(acc[7] * inv) << 16) | (uint)f2bf(acc[6] * inv);
        reinterpret_cast<uint4*>(aggout)[(size_t)w * 16 + c16] = o;
    }
}

// ---------------- MFMA GEMM, persistent waves, register-resident B ----------------
// Wave gw: nt = gw&7 (16-col slice), tile-stream = gw>>3. Preloads its 8
// B-fragments (32 VGPR) once, then grid-strides over 16-row tiles:
// 8 coalesced A-fragment loads + 8 MFMA + 4 stores per tile.
// C (lane l, reg r): row = m0 + (l>>4)*4 + r, col = nt*16 + (l&15).

__global__ __launch_bounds__(256, 6) void k_mm(const ushort* __restrict__ Alow,
                                               const ushort* __restrict__ Ahigh,
                                               const ushort* __restrict__ Wt,
                                               const float* __restrict__ bias,
                                               void* __restrict__ outp,
                                               int n, int ntiles, int relu, int outBf16) {
    int t = threadIdx.x;
    int wv = t >> 6;
    int l = t & 63;
    int lr = l & 15;
    int lk = l >> 4;
    int gw = blockIdx.x * 4 + wv;
    int nt = gw & 7;
    int stream = gw >> 3;

    // preload B fragments (col-slice nt, all of K=256)
    short8v bf[8];
    const ushort* wbase = Wt + (size_t)(nt * 16 + lr) * 256 + lk * 8;
#pragma unroll
    for (int ks = 0; ks < 8; ++ks)
        bf[ks] = *reinterpret_cast<const short8v*>(wbase + ks * 32);

    int col = nt * 16 + lr;
    float bv = bias[col];

    for (int tile = stream; tile < ntiles; tile += MM_STREAMS) {
        int m0 = tile * 16;
        int arow = m0 + lr;
        if (arow >= n) arow = n - 1;  // loads clamped; stores guarded
        const ushort* alo = Alow + (size_t)arow * DD + lk * 8;
        const ushort* ahi = Ahigh + (size_t)arow * DD + lk * 8;

        f32x4 acc = (f32x4){0.f, 0.f, 0.f, 0.f};
#pragma unroll
        for (int ks = 0; ks < 4; ++ks) {
            short8v af = *reinterpret_cast<const short8v*>(alo + ks * 32);
            acc = __builtin_amdgcn_mfma_f32_16x16x32_bf16(af, bf[ks], acc, 0, 0, 0);
        }
#pragma unroll
        for (int ks = 0; ks < 4; ++ks) {
            short8v af = *reinterpret_cast<const short8v*>(ahi + ks * 32);
            acc = __builtin_amdgcn_mfma_f32_16x16x32_bf16(af, bf[ks + 4], acc, 0, 0, 0);
        }

        int row0 = m0 + lk * 4;
#pragma unroll
        for (int r = 0; r < 4; ++r) {
            int row = row0 + r;
            if (row < n) {
                float v = acc[r] + bv;
                if (relu) v = fmaxf(v, 0.f);
                if (outBf16) {
                    reinterpret_cast<ushort*>(outp)[(size_t)row * DD + col] = f2bf(v);
                } else {
                    reinterpret_cast<float*>(outp)[(size_t)row * DD + col] = v;
                }
            }
        }
    }
}

// ---------------- launch ----------------

extern "C" void kernel_launch(void* const* d_in, const int* in_sizes, int n_in,
                              void* d_out, int out_size, void* d_ws, size_t ws_size,
                              hipStream_t stream) {
    const float* x   = (const float*)d_in[0];
    const int*   ei  = (const int*)d_in[1];
    const float* Wl1 = (const float*)d_in[2];
    const float* Wr1 = (const float*)d_in[3];
    const float* b1  = (const float*)d_in[4];
    const float* Wl2 = (const float*)d_in[5];
    const float* Wr2 = (const float*)d_in[6];
    const float* b2  = (const float*)d_in[7];
    float* out = (float*)d_out;

    int n = in_sizes[0] / DD;
    int E = in_sizes[1] / 2;

    int NB   = (n + 255) >> 8;          // buckets (<=256 for n<=65536)
    int nblk = (E + CHUNK - 1) / CHUNK; // partition chunks

    char* ws = (char*)d_ws;
    size_t off = 0;
    auto take = [&](size_t bytes) -> void* {
        void* p = ws + off;
        off = (off + bytes + 255) & ~(size_t)255;
        return p;
    };
    int* cnt       = (int*)take((size_t)n * 4);
    int* rowptr    = (int*)take(((size_t)n + 1) * 4);
    int* incl      = (int*)take((size_t)n * 4);
    int* bsum      = (int*)take(1024);
    int* hist      = (int*)take((size_t)nblk * NB * 4);
    int* bbase     = (int*)take(((size_t)NB + 1) * 4);
    int* eidx      = (int*)take((size_t)E * 4);
    uint2* pairs   = (uint2*)take((size_t)E * 8);
    ushort* xbf    = (ushort*)take((size_t)n * DD * 2);
    ushort* hbf    = (ushort*)take((size_t)n * DD * 2);
    ushort* aggbf  = (ushort*)take((size_t)n * DD * 2);
    ushort* Wt1    = (ushort*)take((size_t)DD * 256 * 2);
    ushort* Wt2    = (ushort*)take((size_t)DD * 256 * 2);

    int scanBlocks = (n + 255) / 256;
    int ntiles = (n + 15) / 16;

    // CSR build
    k_hist<<<nblk, 256, 0, stream>>>(ei, hist, E, NB);
    k_hscan<<<1, 1024, 0, stream>>>(hist, bbase, nblk, NB, E);
    k_scatter<<<nblk, 256, 0, stream>>>(ei, hist, pairs, E, NB);
    k_cntb<<<NB, 256, 0, stream>>>(pairs, bbase, cnt, n);
    k_scan1<<<scanBlocks, 256, 0, stream>>>(cnt, incl, bsum, n);
    k_scan2<<<1, 256, 0, stream>>>(bsum, scanBlocks);
    k_scan3<<<scanBlocks, 256, 0, stream>>>(cnt, incl, bsum, rowptr, n, E);
    k_fill3<<<NB, 256, 0, stream>>>(pairs, bbase, rowptr, eidx, n);

    // dtype prep
    int n4 = n * DD / 4;
    k_cast<<<(n4 + 255) / 256, 256, 0, stream>>>(x, xbf, n4);
    k_prepw<<<128, 256, 0, stream>>>(Wl1, Wr1, Wt1);
    k_prepw<<<128, 256, 0, stream>>>(Wl2, Wr2, Wt2);

    int aggBlocks = (n + 3) / 4;            // 4 waves (nodes) / block
    int mmBlocks  = MM_STREAMS * 8 / 4;     // 2048 blocks (8192 waves)

    // Layer 1: h = relu(mean_agg(xbf) @ Wl1 + b1 + xbf @ Wr1)
    k_aggb<<<aggBlocks, 256, 0, stream>>>(xbf, rowptr, eidx, aggbf, n);
    k_mm<<<mmBlocks, 256, 0, stream>>>(aggbf, xbf, Wt1, b1, hbf, n, ntiles, 1, 1);
    // Layer 2: out = mean_agg(hbf) @ Wl2 + b2 + hbf @ Wr2
    k_aggb<<<aggBlocks, 256, 0, stream>>>(hbf, rowptr, eidx, aggbf, n);
    k_mm<<<mmBlocks, 256, 0, stream>>>(aggbf, hbf, Wt2, b2, out, n, ntiles, 0, 0);
}